// Round 1
// baseline (163.293 us; speedup 1.0000x reference)
//
#include <hip/hip_runtime.h>

// PINN fused forward + u_x + u_xx for a 1->10->10->10->1 tanh MLP.
// Forward-mode AD propagated analytically: per layer carry (t, g, s) =
// (value, d/dx, d2/dx2) per hidden node. fp32 throughout.
//
// Layout decisions:
//  - weights (250 floats) staged to LDS once per block; W2/W3 rows padded to
//    12 floats (48B) so each row reads as 3x ds_read_b128, 16B-aligned.
//  - 2 samples per thread: shares every weight read across 6 FMAs, coalesced
//    float2 load of x and float2 stores of the (N,3) output rows.
//  - tanh: t = 1 - 2r, r = rcp(1+exp(2z)); sech^2 = (2r)^2 * e  (no 1-t^2
//    cancellation; abs err ~1e-7, threshold is 5.2e-3).

#define H  10
#define RS 12  // padded LDS row stride for W2/W3 (multiple of 4 floats -> 16B)

__global__ __launch_bounds__(256) void pinn_fused(
    const float* __restrict__ x,
    const float* __restrict__ W1, const float* __restrict__ b1,
    const float* __restrict__ W2, const float* __restrict__ b2,
    const float* __restrict__ W3, const float* __restrict__ b3,
    const float* __restrict__ W4,
    float* __restrict__ out, int n)
{
    __shared__ __align__(16) float sW2[H * RS];
    __shared__ __align__(16) float sW3[H * RS];
    __shared__ float sW1[H], sB1[H], sC1[H], sB2[H], sB3[H], sW4[H];

    const int tid = threadIdx.x;
    if (tid < H * RS) {
        const int r = tid / RS, c = tid - r * RS;
        sW2[tid] = (c < H) ? W2[r * H + c] : 0.f;
        sW3[tid] = (c < H) ? W3[r * H + c] : 0.f;
    }
    if (tid < H) {
        const float w = W1[tid];
        sW1[tid] = w;
        sC1[tid] = -2.f * w * w;   // coefficient for layer-1 second deriv
        sB1[tid] = b1[tid];
        sB2[tid] = b2[tid];
        sB3[tid] = b3[tid];
        sW4[tid] = W4[tid];
    }
    __syncthreads();

    const int i0 = 2 * (blockIdx.x * 256 + tid);
    if (i0 >= n) return;
    const bool two = (i0 + 1 < n);

    float xa, xb;
    if (two) { const float2 xv = *(const float2*)(x + i0); xa = xv.x; xb = xv.y; }
    else     { xa = x[i0]; xb = 0.f; }

    // per-node state for 2 samples: t (value), g (1st deriv), s (2nd deriv)
    float ta_[H], tb_[H], ga_[H], gb_[H], sa_[H], sb_[H];

    // ---- layer 1: z = x*W1 + b1 ; z' = W1 ; z'' = 0 ----
#pragma unroll
    for (int j = 0; j < H; ++j) {
        const float w = sW1[j], bb = sB1[j], c = sC1[j];
        {
            const float z = fmaf(xa, w, bb);
            const float e = __expf(2.f * z);
            const float r = __builtin_amdgcn_rcpf(1.f + e);
            const float q = r + r;
            const float t = 1.f - q;
            const float d = q * q * e;        // sech^2(z)
            ta_[j] = t; ga_[j] = d * w; sa_[j] = t * d * c;
        }
        {
            const float z = fmaf(xb, w, bb);
            const float e = __expf(2.f * z);
            const float r = __builtin_amdgcn_rcpf(1.f + e);
            const float q = r + r;
            const float t = 1.f - q;
            const float d = q * q * e;
            tb_[j] = t; gb_[j] = d * w; sb_[j] = t * d * c;
        }
    }

    // ---- hidden layers 2 and 3 ----
#define HIDDEN_LAYER(SW, SB)                                                  \
    {                                                                         \
        float za[H], zb[H], pa[H], pb[H], qa[H], qb[H];                       \
        _Pragma("unroll")                                                     \
        for (int k = 0; k < H; ++k) {                                         \
            const float bk = SB[k];                                           \
            za[k] = bk; zb[k] = bk;                                           \
            pa[k] = 0.f; pb[k] = 0.f; qa[k] = 0.f; qb[k] = 0.f;               \
        }                                                                     \
        _Pragma("unroll")                                                     \
        for (int j = 0; j < H; ++j) {                                         \
            const float4* row = (const float4*)(SW + j * RS);                 \
            const float4 w0 = row[0], w1v = row[1], w2v = row[2];             \
            const float wr[H] = {w0.x, w0.y, w0.z, w0.w,                      \
                                 w1v.x, w1v.y, w1v.z, w1v.w,                  \
                                 w2v.x, w2v.y};                               \
            const float tja = ta_[j], tjb = tb_[j];                           \
            const float gja = ga_[j], gjb = gb_[j];                           \
            const float sja = sa_[j], sjb = sb_[j];                           \
            _Pragma("unroll")                                                 \
            for (int k = 0; k < H; ++k) {                                     \
                za[k] = fmaf(tja, wr[k], za[k]);                              \
                zb[k] = fmaf(tjb, wr[k], zb[k]);                              \
                pa[k] = fmaf(gja, wr[k], pa[k]);                              \
                pb[k] = fmaf(gjb, wr[k], pb[k]);                              \
                qa[k] = fmaf(sja, wr[k], qa[k]);                              \
                qb[k] = fmaf(sjb, wr[k], qb[k]);                              \
            }                                                                 \
        }                                                                     \
        _Pragma("unroll")                                                     \
        for (int k = 0; k < H; ++k) {                                         \
            {                                                                 \
                const float zp = pa[k], zpp = qa[k];                          \
                const float e = __expf(2.f * za[k]);                          \
                const float r = __builtin_amdgcn_rcpf(1.f + e);               \
                const float q = r + r;                                        \
                const float t = 1.f - q;                                      \
                const float d = q * q * e;                                    \
                const float t2 = t + t;                                       \
                const float w2 = zp * zp;                                     \
                ta_[k] = t;                                                   \
                ga_[k] = d * zp;                                              \
                sa_[k] = d * fmaf(-t2, w2, zpp);                              \
            }                                                                 \
            {                                                                 \
                const float zp = pb[k], zpp = qb[k];                          \
                const float e = __expf(2.f * zb[k]);                          \
                const float r = __builtin_amdgcn_rcpf(1.f + e);               \
                const float q = r + r;                                        \
                const float t = 1.f - q;                                      \
                const float d = q * q * e;                                    \
                const float t2 = t + t;                                       \
                const float w2 = zp * zp;                                     \
                tb_[k] = t;                                                   \
                gb_[k] = d * zp;                                              \
                sb_[k] = d * fmaf(-t2, w2, zpp);                              \
            }                                                                 \
        }                                                                     \
    }

    HIDDEN_LAYER(sW2, sB2)
    HIDDEN_LAYER(sW3, sB3)
#undef HIDDEN_LAYER

    // ---- output layer: u = h3 @ W4 (no bias) ----
    float ua = 0.f, uxa = 0.f, uxxa = 0.f;
    float ub = 0.f, uxb = 0.f, uxxb = 0.f;
#pragma unroll
    for (int k = 0; k < H; ++k) {
        const float w = sW4[k];
        ua   = fmaf(ta_[k], w, ua);
        uxa  = fmaf(ga_[k], w, uxa);
        uxxa = fmaf(sa_[k], w, uxxa);
        ub   = fmaf(tb_[k], w, ub);
        uxb  = fmaf(gb_[k], w, uxb);
        uxxb = fmaf(sb_[k], w, uxxb);
    }

    float* o = out + i0 * 3;
    if (two) {
        ((float2*)o)[0] = make_float2(ua, uxa);
        ((float2*)o)[1] = make_float2(uxxa, ub);
        ((float2*)o)[2] = make_float2(uxb, uxxb);
    } else {
        o[0] = ua; o[1] = uxa; o[2] = uxxa;
    }
}

extern "C" void kernel_launch(void* const* d_in, const int* in_sizes, int n_in,
                              void* d_out, int out_size, void* d_ws, size_t ws_size,
                              hipStream_t stream) {
    const float* x  = (const float*)d_in[0];
    const float* W1 = (const float*)d_in[1];
    const float* b1 = (const float*)d_in[2];
    const float* W2 = (const float*)d_in[3];
    const float* b2 = (const float*)d_in[4];
    const float* W3 = (const float*)d_in[5];
    const float* b3 = (const float*)d_in[6];
    const float* W4 = (const float*)d_in[7];
    float* out = (float*)d_out;

    const int n = in_sizes[0];
    const int threads = 256;
    const int blocks = (n / 2 + threads - 1) / threads;  // 2 samples/thread
    pinn_fused<<<blocks, threads, 0, stream>>>(x, W1, b1, W2, b2, W3, b3, W4, out, n);
}

// Round 2
// 122.329 us; speedup vs baseline: 1.3349x; 1.3349x over previous
//
#include <hip/hip_runtime.h>

// PINN fused forward + u_x + u_xx for a 1->10->10->10->1 tanh MLP.
// Round 2: 1 sample/thread (halve VGPR state -> more waves/SIMD), trimmed
// tanh algebra:
//   t = fma(-2, r, 1), r = rcp(1+exp(2z))        [6 ops to t,d incl. exp/rcp]
//   d = sech^2 = fma(-t, t, 1)                   [abs err ~1e-7 << 5.2e-3 thr]
//   g_out = d*p ; s_out = d*q - 2*t*p^2*d = fma(-(2t*p), g_out, d*q)
// Accumulator init folded into the j==0 row of each hidden-layer matvec.
// Weights staged once per block into LDS; W2/W3 rows padded to 12 floats so
// each row is 3x ds_read_b128 (broadcast reads, no bank conflicts).

#define H  10
#define RS 12

__global__ __launch_bounds__(256, 4) void pinn_fused(
    const float* __restrict__ x,
    const float* __restrict__ W1, const float* __restrict__ b1,
    const float* __restrict__ W2, const float* __restrict__ b2,
    const float* __restrict__ W3, const float* __restrict__ b3,
    const float* __restrict__ W4,
    float* __restrict__ out, int n)
{
    __shared__ __align__(16) float sW2[H * RS];
    __shared__ __align__(16) float sW3[H * RS];
    __shared__ float sW1[H], sB1[H], sC1[H], sB2[H], sB3[H], sW4[H];

    const int tid = threadIdx.x;
    if (tid < H * RS) {
        const int r = tid / RS, c = tid - r * RS;
        sW2[tid] = (c < H) ? W2[r * H + c] : 0.f;
        sW3[tid] = (c < H) ? W3[r * H + c] : 0.f;
    }
    if (tid < H) {
        const float w = W1[tid];
        sW1[tid] = w;
        sC1[tid] = -2.f * w;       // s1 = (t*c)*g with c = -2w  (s = -2 t d w^2)
        sB1[tid] = b1[tid];
        sB2[tid] = b2[tid];
        sB3[tid] = b3[tid];
        sW4[tid] = W4[tid];
    }
    __syncthreads();

    const int i = blockIdx.x * 256 + tid;
    if (i >= n) return;
    const float xv = x[i];

    // per-node jet state: t (value), g (d/dx), s (d2/dx2)
    float t_[H], g_[H], s_[H];

    // ---- layer 1: z = x*w + b ; z' = w ; z'' = 0 ----
#pragma unroll
    for (int j = 0; j < H; ++j) {
        const float w = sW1[j];
        const float z = fmaf(xv, w, sB1[j]);
        const float e = __expf(2.f * z);
        const float r = __builtin_amdgcn_rcpf(1.f + e);
        const float t = fmaf(-2.f, r, 1.f);
        const float d = fmaf(-t, t, 1.f);      // sech^2(z)
        const float g = d * w;
        t_[j] = t;
        g_[j] = g;
        s_[j] = (t * sC1[j]) * g;              // -2 t d w^2
    }

    // ---- hidden layers 2 and 3 ----
#define HIDDEN_LAYER(SW, SB)                                                  \
    {                                                                         \
        float z_[H], p_[H], q_[H];                                            \
        {   /* j == 0: init accumulators (no zero-fill movs) */               \
            const float4* row = (const float4*)(SW);                          \
            const float4 w0 = row[0], w1v = row[1], w2v = row[2];             \
            const float wr[H] = {w0.x, w0.y, w0.z, w0.w,                      \
                                 w1v.x, w1v.y, w1v.z, w1v.w,                  \
                                 w2v.x, w2v.y};                               \
            const float tj = t_[0], gj = g_[0], sj = s_[0];                   \
            _Pragma("unroll")                                                 \
            for (int k = 0; k < H; ++k) {                                     \
                z_[k] = fmaf(tj, wr[k], SB[k]);                               \
                p_[k] = gj * wr[k];                                           \
                q_[k] = sj * wr[k];                                           \
            }                                                                 \
        }                                                                     \
        _Pragma("unroll")                                                     \
        for (int j = 1; j < H; ++j) {                                         \
            const float4* row = (const float4*)(SW + j * RS);                 \
            const float4 w0 = row[0], w1v = row[1], w2v = row[2];             \
            const float wr[H] = {w0.x, w0.y, w0.z, w0.w,                      \
                                 w1v.x, w1v.y, w1v.z, w1v.w,                  \
                                 w2v.x, w2v.y};                               \
            const float tj = t_[j], gj = g_[j], sj = s_[j];                   \
            _Pragma("unroll")                                                 \
            for (int k = 0; k < H; ++k) {                                     \
                z_[k] = fmaf(tj, wr[k], z_[k]);                               \
                p_[k] = fmaf(gj, wr[k], p_[k]);                               \
                q_[k] = fmaf(sj, wr[k], q_[k]);                               \
            }                                                                 \
        }                                                                     \
        _Pragma("unroll")                                                     \
        for (int k = 0; k < H; ++k) {                                         \
            const float p = p_[k], q = q_[k];                                 \
            const float e = __expf(2.f * z_[k]);                              \
            const float r = __builtin_amdgcn_rcpf(1.f + e);                   \
            const float t = fmaf(-2.f, r, 1.f);                               \
            const float d = fmaf(-t, t, 1.f);                                 \
            const float g = d * p;                                            \
            const float m = (t + t) * p;                                      \
            t_[k] = t;                                                        \
            g_[k] = g;                                                        \
            s_[k] = fmaf(-m, g, d * q);                                       \
        }                                                                     \
    }

    HIDDEN_LAYER(sW2, sB2)
    HIDDEN_LAYER(sW3, sB3)
#undef HIDDEN_LAYER

    // ---- output layer: u = h3 @ W4 (no bias) ----
    float u, ux, uxx;
    {
        const float w0 = sW4[0];
        u = t_[0] * w0; ux = g_[0] * w0; uxx = s_[0] * w0;
    }
#pragma unroll
    for (int k = 1; k < H; ++k) {
        const float w = sW4[k];
        u   = fmaf(t_[k], w, u);
        ux  = fmaf(g_[k], w, ux);
        uxx = fmaf(s_[k], w, uxx);
    }

    float* o = out + i * 3;
    o[0] = u; o[1] = ux; o[2] = uxx;
}

extern "C" void kernel_launch(void* const* d_in, const int* in_sizes, int n_in,
                              void* d_out, int out_size, void* d_ws, size_t ws_size,
                              hipStream_t stream) {
    const float* x  = (const float*)d_in[0];
    const float* W1 = (const float*)d_in[1];
    const float* b1 = (const float*)d_in[2];
    const float* W2 = (const float*)d_in[3];
    const float* b2 = (const float*)d_in[4];
    const float* W3 = (const float*)d_in[5];
    const float* b3 = (const float*)d_in[6];
    const float* W4 = (const float*)d_in[7];
    float* out = (float*)d_out;

    const int n = in_sizes[0];
    const int threads = 256;
    const int blocks = (n + threads - 1) / threads;  // 1 sample/thread
    pinn_fused<<<blocks, threads, 0, stream>>>(x, W1, b1, W2, b2, W3, b3, W4, out, n);
}